// Round 1
// baseline (1494.426 us; speedup 1.0000x reference)
//
#include <hip/hip_runtime.h>

// AttackLSTM: 6 stacked LSTM layers. B=256, T=512.
// a0:(1->64) a1:(64->64) a2:(64->64) b0:(64->1) b1:(1->1) b2:(1->1)
// Strategy R1 (fp32 baseline):
//  - a-layers: 1 block per batch element (256 blocks = 256 CUs), 256 threads =
//    one thread per gate row g. Weight rows in VGPRs; h and x broadcast via LDS.
//  - b-stack: parallel input-projection kernel for b0, then a single-block
//    fused b0->b1->b2 elementwise recurrence (one thread per batch element).

#define BB 256
#define TT 512

__device__ __forceinline__ float sig_(float x) {
  // 1/(1+2^(-x*log2e))
  return __builtin_amdgcn_rcpf(1.f + __builtin_amdgcn_exp2f(-1.44269504f * x));
}
__device__ __forceinline__ float tanh_(float x) {
  // 2/(1+2^(-2x*log2e)) - 1
  return __builtin_fmaf(2.f, __builtin_amdgcn_rcpf(1.f + __builtin_amdgcn_exp2f(-2.885390082f * x)), -1.f);
}

template <int DIN>
__global__ __launch_bounds__(256, 1) void lstm_layer_k(
    const float* __restrict__ x,     // [B,T,DIN]
    const float* __restrict__ w_ih,  // [256,DIN]
    const float* __restrict__ w_hh,  // [256,64]
    const float* __restrict__ b_ih,  // [256]
    const float* __restrict__ b_hh,  // [256]
    float* __restrict__ out)         // [B,T,64]
{
  const int b = blockIdx.x;
  const int g = threadIdx.x;  // gate row 0..255 (i:0-63, f:64-127, g:128-191, o:192-255)

  __shared__ float h_s[64];
  __shared__ float x_s[2][64];
  __shared__ float act_s[256];

  // hidden weights: row g of w_hh into registers (64 VGPRs)
  float wh[64];
#pragma unroll
  for (int i = 0; i < 16; ++i) {
    float4 v = reinterpret_cast<const float4*>(w_hh + g * 64)[i];
    wh[4 * i] = v.x; wh[4 * i + 1] = v.y; wh[4 * i + 2] = v.z; wh[4 * i + 3] = v.w;
  }
  float wi[DIN == 1 ? 4 : 64];
  if constexpr (DIN == 64) {
#pragma unroll
    for (int i = 0; i < 16; ++i) {
      float4 v = reinterpret_cast<const float4*>(w_ih + g * 64)[i];
      wi[4 * i] = v.x; wi[4 * i + 1] = v.y; wi[4 * i + 2] = v.z; wi[4 * i + 3] = v.w;
    }
  } else {
    wi[0] = w_ih[g];
  }
  const float bias = b_ih[g] + b_hh[g];

  float c = 0.f;  // cell state, valid for g<64 only
  if (g < 64) {
    h_s[g] = 0.f;
    if constexpr (DIN == 64) x_s[0][g] = x[((size_t)b * TT) * 64 + g];
  }
  __syncthreads();

  const float* xb = x + (size_t)b * TT * DIN;
  float* ob = out + (size_t)b * TT * 64;

  for (int t = 0; t < TT; ++t) {
    // wave0 prefetches next timestep's input row (latency hidden behind FMAs)
    float xn = 0.f;
    if constexpr (DIN == 64) {
      if (g < 64 && t + 1 < TT) xn = xb[(t + 1) * 64 + g];
    }
    float x0 = 0.f;
    if constexpr (DIN == 1) x0 = xb[t];  // broadcast load, L1-resident

    // gate pre-activation: bias + w_hh[g,:]·h + w_ih[g,:]·x
    float a0 = bias, a1 = 0.f, a2 = 0.f, a3 = 0.f;
    const float4* hp = reinterpret_cast<const float4*>(h_s);
#pragma unroll
    for (int i = 0; i < 16; ++i) {
      float4 hv = hp[i];
      a0 = __builtin_fmaf(wh[4 * i], hv.x, a0);
      a1 = __builtin_fmaf(wh[4 * i + 1], hv.y, a1);
      a2 = __builtin_fmaf(wh[4 * i + 2], hv.z, a2);
      a3 = __builtin_fmaf(wh[4 * i + 3], hv.w, a3);
    }
    if constexpr (DIN == 64) {
      const float4* xp = reinterpret_cast<const float4*>(x_s[t & 1]);
#pragma unroll
      for (int i = 0; i < 16; ++i) {
        float4 xv = xp[i];
        a0 = __builtin_fmaf(wi[4 * i], xv.x, a0);
        a1 = __builtin_fmaf(wi[4 * i + 1], xv.y, a1);
        a2 = __builtin_fmaf(wi[4 * i + 2], xv.z, a2);
        a3 = __builtin_fmaf(wi[4 * i + 3], xv.w, a3);
      }
    } else {
      a0 = __builtin_fmaf(wi[0], x0, a0);
    }
    float pre = (a0 + a1) + (a2 + a3);
    // gate 'g' (third quarter) uses tanh; i,f,o use sigmoid. Wave-uniform branch.
    float act = ((g >> 6) == 2) ? tanh_(pre) : sig_(pre);
    act_s[g] = act;
    __syncthreads();

    if (g < 64) {
      float gi = act_s[g], gf = act_s[64 + g], gg = act_s[128 + g], go = act_s[192 + g];
      c = __builtin_fmaf(gf, c, gi * gg);
      float hn = go * tanh_(c);
      h_s[g] = hn;
      ob[t * 64 + g] = hn;  // coalesced 256B store
      if constexpr (DIN == 64) {
        if (t + 1 < TT) x_s[(t + 1) & 1][g] = xn;
      }
    }
    __syncthreads();
  }
}

// pre_b0[t][b][gate] = b_ih[gate]+b_hh[gate] + w_ih_b0[gate,:]·a2_out[b,t,:]
// grid: T*4 blocks of 256 threads; block covers one t and 64 batch elements.
__global__ __launch_bounds__(256) void pre_b0_k(
    const float* __restrict__ a2,    // [B,T,64]
    const float* __restrict__ w_ih,  // [4,64]
    const float* __restrict__ b_ih,  // [4]
    const float* __restrict__ b_hh,  // [4]
    float* __restrict__ pre)         // [T,B,4]
{
  __shared__ float w_s[256];
  const int tid = threadIdx.x;
  w_s[tid] = w_ih[tid];
  __syncthreads();

  const int t = blockIdx.x >> 2;
  const int bc = blockIdx.x & 3;
  const int b = bc * 64 + (tid >> 2);
  const int gate = tid & 3;

  const float* row = a2 + ((size_t)b * TT + t) * 64;
  const float* w = w_s + gate * 64;
  float a0 = b_ih[gate] + b_hh[gate], a1 = 0.f, a2v = 0.f, a3 = 0.f;
#pragma unroll
  for (int i = 0; i < 16; ++i) {
    float4 r = reinterpret_cast<const float4*>(row)[i];
    float4 wv = reinterpret_cast<const float4*>(w)[i];
    a0 = __builtin_fmaf(wv.x, r.x, a0);
    a1 = __builtin_fmaf(wv.y, r.y, a1);
    a2v = __builtin_fmaf(wv.z, r.z, a2v);
    a3 = __builtin_fmaf(wv.w, r.w, a3);
  }
  pre[((size_t)t * BB + b) * 4 + gate] = (a0 + a1) + (a2v + a3);
}

// Fused b0->b1->b2 recurrence: one thread per batch element (H=1 layers).
__global__ __launch_bounds__(256, 1) void b_rec_k(
    const float* __restrict__ pre,      // [T,B,4]  (b0 gate pre-activations)
    const float* __restrict__ w_hh_b0,  // [4]
    const float* __restrict__ w_ih_b1,  // [4]
    const float* __restrict__ w_hh_b1,  // [4]
    const float* __restrict__ b_ih_b1,  // [4]
    const float* __restrict__ b_hh_b1,  // [4]
    const float* __restrict__ w_ih_b2,  // [4]
    const float* __restrict__ w_hh_b2,  // [4]
    const float* __restrict__ b_ih_b2,  // [4]
    const float* __restrict__ b_hh_b2,  // [4]
    float* __restrict__ out)            // [B,T]
{
  const int b = threadIdx.x;
  float wh0[4], wi1[4], wh1[4], bb1[4], wi2[4], wh2[4], bb2[4];
#pragma unroll
  for (int k = 0; k < 4; ++k) {
    wh0[k] = w_hh_b0[k];
    wi1[k] = w_ih_b1[k];
    wh1[k] = w_hh_b1[k];
    bb1[k] = b_ih_b1[k] + b_hh_b1[k];
    wi2[k] = w_ih_b2[k];
    wh2[k] = w_hh_b2[k];
    bb2[k] = b_ih_b2[k] + b_hh_b2[k];
  }
  float h0 = 0.f, c0 = 0.f, h1 = 0.f, c1 = 0.f, h2 = 0.f, c2 = 0.f;

  for (int t = 0; t < TT; ++t) {
    float4 p = reinterpret_cast<const float4*>(pre)[t * BB + b];  // coalesced
    // layer b0
    float i0 = sig_(__builtin_fmaf(wh0[0], h0, p.x));
    float f0 = sig_(__builtin_fmaf(wh0[1], h0, p.y));
    float g0 = tanh_(__builtin_fmaf(wh0[2], h0, p.z));
    float o0 = sig_(__builtin_fmaf(wh0[3], h0, p.w));
    c0 = __builtin_fmaf(f0, c0, i0 * g0);
    h0 = o0 * tanh_(c0);
    // layer b1
    float i1 = sig_(bb1[0] + __builtin_fmaf(wi1[0], h0, wh1[0] * h1));
    float f1 = sig_(bb1[1] + __builtin_fmaf(wi1[1], h0, wh1[1] * h1));
    float g1 = tanh_(bb1[2] + __builtin_fmaf(wi1[2], h0, wh1[2] * h1));
    float o1 = sig_(bb1[3] + __builtin_fmaf(wi1[3], h0, wh1[3] * h1));
    c1 = __builtin_fmaf(f1, c1, i1 * g1);
    h1 = o1 * tanh_(c1);
    // layer b2
    float i2 = sig_(bb2[0] + __builtin_fmaf(wi2[0], h1, wh2[0] * h2));
    float f2 = sig_(bb2[1] + __builtin_fmaf(wi2[1], h1, wh2[1] * h2));
    float g2 = tanh_(bb2[2] + __builtin_fmaf(wi2[2], h1, wh2[2] * h2));
    float o2 = sig_(bb2[3] + __builtin_fmaf(wi2[3], h1, wh2[3] * h2));
    c2 = __builtin_fmaf(f2, c2, i2 * g2);
    h2 = o2 * tanh_(c2);

    out[b * TT + t] = h2;
  }
}

extern "C" void kernel_launch(void* const* d_in, const int* in_sizes, int n_in,
                              void* d_out, int out_size, void* d_ws, size_t ws_size,
                              hipStream_t stream) {
  const float* x = (const float*)d_in[0];
  // per-layer params: [w_ih, w_hh, b_ih, b_hh] for a0,a1,a2,b0,b1,b2
  const float* wih_a0 = (const float*)d_in[1];
  const float* whh_a0 = (const float*)d_in[2];
  const float* bih_a0 = (const float*)d_in[3];
  const float* bhh_a0 = (const float*)d_in[4];
  const float* wih_a1 = (const float*)d_in[5];
  const float* whh_a1 = (const float*)d_in[6];
  const float* bih_a1 = (const float*)d_in[7];
  const float* bhh_a1 = (const float*)d_in[8];
  const float* wih_a2 = (const float*)d_in[9];
  const float* whh_a2 = (const float*)d_in[10];
  const float* bih_a2 = (const float*)d_in[11];
  const float* bhh_a2 = (const float*)d_in[12];
  const float* wih_b0 = (const float*)d_in[13];
  const float* whh_b0 = (const float*)d_in[14];
  const float* bih_b0 = (const float*)d_in[15];
  const float* bhh_b0 = (const float*)d_in[16];
  const float* wih_b1 = (const float*)d_in[17];
  const float* whh_b1 = (const float*)d_in[18];
  const float* bih_b1 = (const float*)d_in[19];
  const float* bhh_b1 = (const float*)d_in[20];
  const float* wih_b2 = (const float*)d_in[21];
  const float* whh_b2 = (const float*)d_in[22];
  const float* bih_b2 = (const float*)d_in[23];
  const float* bhh_b2 = (const float*)d_in[24];

  float* ws0 = (float*)d_ws;                       // [B,T,64] fp32 = 33.6 MB
  float* ws1 = ws0 + (size_t)BB * TT * 64;         // [B,T,64] fp32 = 33.6 MB
  float* out = (float*)d_out;                      // [B,T]

  lstm_layer_k<1><<<BB, 256, 0, stream>>>(x, wih_a0, whh_a0, bih_a0, bhh_a0, ws0);
  lstm_layer_k<64><<<BB, 256, 0, stream>>>(ws0, wih_a1, whh_a1, bih_a1, bhh_a1, ws1);
  lstm_layer_k<64><<<BB, 256, 0, stream>>>(ws1, wih_a2, whh_a2, bih_a2, bhh_a2, ws0);
  // b0 input projection into [T,B,4] (reuses ws1; a1 output no longer needed)
  pre_b0_k<<<TT * 4, 256, 0, stream>>>(ws0, wih_b0, bih_b0, bhh_b0, ws1);
  b_rec_k<<<1, 256, 0, stream>>>(ws1, whh_b0, wih_b1, whh_b1, bih_b1, bhh_b1,
                                 wih_b2, whh_b2, bih_b2, bhh_b2, out);
}

// Round 2
// 1141.437 us; speedup vs baseline: 1.3093x; 1.3093x over previous
//
#include <hip/hip_runtime.h>

// AttackLSTM R2: 6 stacked LSTM layers. B=256, T=512.
// a0:(1->64) a1:(64->64) a2:(64->64) b0:(64->1) b1:(1->1) b2:(1->1)
//  - One block per batch element (256 blocks), 256 threads.
//  - Thread g -> (hid = g>>2, gate = g&3), weight row = gate*64+hid.
//    Gates of one hidden unit sit in a lane-quad -> DPP quad-broadcast
//    combine, redundant c/h update, ONE barrier per step (double-buffered h).
//  - Weights pinned in VGPRs via empty asm (compiler was re-fetching them
//    from L2 every step in R1: VGPR_Count=84 < 128 weight floats).
//  - Next-layer input projection fused into the producer's h-broadcast
//    (second 64-FMA dot on the already-resident h float4s), so the
//    consumer reads 1 coalesced float/thread/step instead of an x-dot.

#define BB 256
#define TT 512

__device__ __forceinline__ float sig_(float x) {
  return __builtin_amdgcn_rcpf(1.f + __builtin_amdgcn_exp2f(-1.44269504f * x));
}
__device__ __forceinline__ float tanh_(float x) {
  return __builtin_fmaf(2.f, __builtin_amdgcn_rcpf(1.f + __builtin_amdgcn_exp2f(-2.88539008f * x)), -1.f);
}

// DPP quad_perm broadcast of quad-lane K to all 4 lanes of each quad.
template <int K>
__device__ __forceinline__ float qb_(float v) {
  return __int_as_float(__builtin_amdgcn_update_dpp(
      0, __float_as_int(v), (K | (K << 2) | (K << 4) | (K << 6)), 0xF, 0xF, true));
}

// Pin values in VGPRs: asm outputs cannot be rematerialized.
#define KEEP4(a, i) asm volatile("" : "+v"(a[(i)]), "+v"(a[(i)+1]), "+v"(a[(i)+2]), "+v"(a[(i)+3]))
#define KEEP16(a, i) do { KEEP4(a, (i)); KEEP4(a, (i)+4); KEEP4(a, (i)+8); KEEP4(a, (i)+12); } while (0)
#define KEEP64(a) do { KEEP16(a, 0); KEEP16(a, 16); KEEP16(a, 32); KEEP16(a, 48); } while (0)

// MODE 0: layer a0 (input = x [B,T,1]; proj-out = pre for a1, [B,T,256] PreT)
// MODE 1: layer a1 (input = pre_in [B,T,256] PreT; proj-out overwrites same buffer)
// MODE 2: layer a2 (input = pre_in; proj-out = pre_b0 [T,B,4] fp32, incl. b0 biases)
template <int MODE, typename PreT>
__global__ __launch_bounds__(256, 1) void lstm_k(
    const float* __restrict__ x,      // MODE0 only
    const PreT* pre_in,               // MODE1/2 (may alias pre_out)
    const float* __restrict__ w_ih0,  // MODE0 only: [256,1]
    const float* __restrict__ w_hh,   // [256,64]
    const float* __restrict__ b_ih,
    const float* __restrict__ b_hh,
    const float* __restrict__ w_next, // [256,64] (MODE0/1) or [4,64] (MODE2)
    const float* __restrict__ bn_ih,  // MODE2: b0 biases
    const float* __restrict__ bn_hh,
    PreT* pre_out,                    // MODE0/1
    float* __restrict__ pre_b0)       // MODE2
{
  const int b = blockIdx.x;
  const int g = threadIdx.x;
  const int q = g & 3;    // gate: 0=i 1=f 2=g 3=o
  const int hid = g >> 2; // hidden unit 0..63
  const int row = q * 64 + hid;

  __shared__ float h_s[2][64];

  // ---- load weights into VGPRs and pin them ----
  float wh[64];
  {
    const float4* p = reinterpret_cast<const float4*>(w_hh + row * 64);
#pragma unroll
    for (int i = 0; i < 16; ++i) {
      float4 v = p[i];
      wh[4 * i] = v.x; wh[4 * i + 1] = v.y; wh[4 * i + 2] = v.z; wh[4 * i + 3] = v.w;
    }
  }
  float wn[64];
  {
    const int nrow = (MODE == 2) ? q : row;  // MODE2: w_ih_b0 row = gate
    const float4* p = reinterpret_cast<const float4*>(w_next + nrow * 64);
#pragma unroll
    for (int i = 0; i < 16; ++i) {
      float4 v = p[i];
      wn[4 * i] = v.x; wn[4 * i + 1] = v.y; wn[4 * i + 2] = v.z; wn[4 * i + 3] = v.w;
    }
  }
  KEEP64(wh);
  KEEP64(wn);

  const float bias = b_ih[row] + b_hh[row];
  float wi0 = 0.f, bn0 = 0.f;
  if constexpr (MODE == 0) wi0 = w_ih0[row];
  if constexpr (MODE == 2) bn0 = bn_ih[q] + bn_hh[q];

  if (g < 64) { h_s[0][g] = 0.f; }
  __syncthreads();

  float c = 0.f;  // cell state for `hid` (replicated across the quad)

  // input pipeline: pv = recurrence input addend for step t
  float pv;
  if constexpr (MODE == 0) pv = x[(size_t)b * TT];
  else pv = (float)pre_in[((size_t)b * TT) * 256 + g];

  for (int t = 0; t < TT; ++t) {
    float nv = 0.f;
    if (t + 1 < TT) {
      if constexpr (MODE == 0) nv = x[(size_t)b * TT + t + 1];
      else nv = (float)pre_in[((size_t)b * TT + t + 1) * 256 + g];
    }

    float ar0, ar1 = 0.f, ar2 = 0.f, ar3 = 0.f;
    if constexpr (MODE == 0) ar0 = __builtin_fmaf(wi0, pv, bias);
    else ar0 = bias + pv;
    float ap0 = 0.f, ap1 = 0.f, ap2 = 0.f, ap3 = 0.f;

    const float4* hp = reinterpret_cast<const float4*>(h_s[t & 1]);
#pragma unroll
    for (int i = 0; i < 16; ++i) {
      float4 hv = hp[i];
      ar0 = __builtin_fmaf(wh[4 * i],     hv.x, ar0);
      ar1 = __builtin_fmaf(wh[4 * i + 1], hv.y, ar1);
      ar2 = __builtin_fmaf(wh[4 * i + 2], hv.z, ar2);
      ar3 = __builtin_fmaf(wh[4 * i + 3], hv.w, ar3);
      ap0 = __builtin_fmaf(wn[4 * i],     hv.x, ap0);
      ap1 = __builtin_fmaf(wn[4 * i + 1], hv.y, ap1);
      ap2 = __builtin_fmaf(wn[4 * i + 2], hv.z, ap2);
      ap3 = __builtin_fmaf(wn[4 * i + 3], hv.w, ap3);
    }
    float prer = (ar0 + ar1) + (ar2 + ar3);
    float proj = (ap0 + ap1) + (ap2 + ap3);  // projection of h_{t-1} -> belongs to step t-1

    // activation: gate 2 (g) tanh, others sigmoid — branch-free
    float sc = (q == 2) ? -2.88539008f : -1.44269504f;
    float e = __builtin_amdgcn_exp2f(sc * prer);
    float r = __builtin_amdgcn_rcpf(1.f + e);
    float act = (q == 2) ? __builtin_fmaf(2.f, r, -1.f) : r;

    // quad gather of the 4 gates (no LDS, no barrier)
    float gi = qb_<0>(act);
    float gf = qb_<1>(act);
    float gg = qb_<2>(act);
    float go = qb_<3>(act);

    c = __builtin_fmaf(gf, c, gi * gg);
    float h = go * tanh_(c);
    if (q == 0) h_s[(t + 1) & 1][hid] = h;

    // store lagged projection output (h_{t-1} -> index t-1)
    if (t > 0) {
      if constexpr (MODE == 2) {
        if (g < 4) pre_b0[((size_t)(t - 1) * BB + b) * 4 + g] = proj + bn0;
      } else {
        pre_out[((size_t)b * TT + (t - 1)) * 256 + g] = (PreT)proj;
      }
    }

    pv = nv;
    __syncthreads();
  }

  // epilogue: projection of h_{TT-1}
  {
    const float4* hp = reinterpret_cast<const float4*>(h_s[TT & 1]);
    float ap0 = 0.f, ap1 = 0.f, ap2 = 0.f, ap3 = 0.f;
#pragma unroll
    for (int i = 0; i < 16; ++i) {
      float4 hv = hp[i];
      ap0 = __builtin_fmaf(wn[4 * i],     hv.x, ap0);
      ap1 = __builtin_fmaf(wn[4 * i + 1], hv.y, ap1);
      ap2 = __builtin_fmaf(wn[4 * i + 2], hv.z, ap2);
      ap3 = __builtin_fmaf(wn[4 * i + 3], hv.w, ap3);
    }
    float proj = (ap0 + ap1) + (ap2 + ap3);
    if constexpr (MODE == 2) {
      if (g < 4) pre_b0[((size_t)(TT - 1) * BB + b) * 4 + g] = proj + bn0;
    } else {
      pre_out[((size_t)b * TT + (TT - 1)) * 256 + g] = (PreT)proj;
    }
  }
}

// Fused b0->b1->b2 recurrence: one thread per batch element (H=1 layers).
__global__ __launch_bounds__(256, 1) void b_rec_k(
    const float* __restrict__ pre,      // [T,B,4] (b0 pre-activations incl. biases)
    const float* __restrict__ w_hh_b0,  // [4]
    const float* __restrict__ w_ih_b1,  // [4]
    const float* __restrict__ w_hh_b1,  // [4]
    const float* __restrict__ b_ih_b1,  // [4]
    const float* __restrict__ b_hh_b1,  // [4]
    const float* __restrict__ w_ih_b2,  // [4]
    const float* __restrict__ w_hh_b2,  // [4]
    const float* __restrict__ b_ih_b2,  // [4]
    const float* __restrict__ b_hh_b2,  // [4]
    float* __restrict__ out)            // [B,T]
{
  const int b = threadIdx.x;
  float wh0[4], wi1[4], wh1[4], bb1[4], wi2[4], wh2[4], bb2[4];
#pragma unroll
  for (int k = 0; k < 4; ++k) {
    wh0[k] = w_hh_b0[k];
    wi1[k] = w_ih_b1[k];
    wh1[k] = w_hh_b1[k];
    bb1[k] = b_ih_b1[k] + b_hh_b1[k];
    wi2[k] = w_ih_b2[k];
    wh2[k] = w_hh_b2[k];
    bb2[k] = b_ih_b2[k] + b_hh_b2[k];
  }
  float h0 = 0.f, c0 = 0.f, h1 = 0.f, c1 = 0.f, h2 = 0.f, c2 = 0.f;

  for (int t = 0; t < TT; ++t) {
    float4 p = reinterpret_cast<const float4*>(pre)[t * BB + b];  // coalesced
    float i0 = sig_(__builtin_fmaf(wh0[0], h0, p.x));
    float f0 = sig_(__builtin_fmaf(wh0[1], h0, p.y));
    float g0 = tanh_(__builtin_fmaf(wh0[2], h0, p.z));
    float o0 = sig_(__builtin_fmaf(wh0[3], h0, p.w));
    c0 = __builtin_fmaf(f0, c0, i0 * g0);
    h0 = o0 * tanh_(c0);

    float i1 = sig_(bb1[0] + __builtin_fmaf(wi1[0], h0, wh1[0] * h1));
    float f1 = sig_(bb1[1] + __builtin_fmaf(wi1[1], h0, wh1[1] * h1));
    float g1 = tanh_(bb1[2] + __builtin_fmaf(wi1[2], h0, wh1[2] * h1));
    float o1 = sig_(bb1[3] + __builtin_fmaf(wi1[3], h0, wh1[3] * h1));
    c1 = __builtin_fmaf(f1, c1, i1 * g1);
    h1 = o1 * tanh_(c1);

    float i2 = sig_(bb2[0] + __builtin_fmaf(wi2[0], h1, wh2[0] * h2));
    float f2 = sig_(bb2[1] + __builtin_fmaf(wi2[1], h1, wh2[1] * h2));
    float g2 = tanh_(bb2[2] + __builtin_fmaf(wi2[2], h1, wh2[2] * h2));
    float o2 = sig_(bb2[3] + __builtin_fmaf(wi2[3], h1, wh2[3] * h2));
    c2 = __builtin_fmaf(f2, c2, i2 * g2);
    h2 = o2 * tanh_(c2);

    out[b * TT + t] = h2;
  }
}

template <typename PreT>
static void launch_all(void* const* d_in, void* d_out, void* d_ws, hipStream_t stream) {
  const float* x      = (const float*)d_in[0];
  const float* wih_a0 = (const float*)d_in[1];
  const float* whh_a0 = (const float*)d_in[2];
  const float* bih_a0 = (const float*)d_in[3];
  const float* bhh_a0 = (const float*)d_in[4];
  const float* wih_a1 = (const float*)d_in[5];
  const float* whh_a1 = (const float*)d_in[6];
  const float* bih_a1 = (const float*)d_in[7];
  const float* bhh_a1 = (const float*)d_in[8];
  const float* wih_a2 = (const float*)d_in[9];
  const float* whh_a2 = (const float*)d_in[10];
  const float* bih_a2 = (const float*)d_in[11];
  const float* bhh_a2 = (const float*)d_in[12];
  const float* wih_b0 = (const float*)d_in[13];
  const float* whh_b0 = (const float*)d_in[14];
  const float* bih_b0 = (const float*)d_in[15];
  const float* bhh_b0 = (const float*)d_in[16];
  const float* wih_b1 = (const float*)d_in[17];
  const float* whh_b1 = (const float*)d_in[18];
  const float* bih_b1 = (const float*)d_in[19];
  const float* bhh_b1 = (const float*)d_in[20];
  const float* wih_b2 = (const float*)d_in[21];
  const float* whh_b2 = (const float*)d_in[22];
  const float* bih_b2 = (const float*)d_in[23];
  const float* bhh_b2 = (const float*)d_in[24];

  PreT* preA = (PreT*)d_ws;                                   // [B,T,256]
  float* pb0 = (float*)((char*)d_ws + (size_t)BB * TT * 256 * sizeof(PreT));  // [T,B,4]
  float* out = (float*)d_out;

  lstm_k<0, PreT><<<BB, 256, 0, stream>>>(x, nullptr, wih_a0, whh_a0, bih_a0, bhh_a0,
                                          wih_a1, nullptr, nullptr, preA, nullptr);
  lstm_k<1, PreT><<<BB, 256, 0, stream>>>(nullptr, preA, nullptr, whh_a1, bih_a1, bhh_a1,
                                          wih_a2, nullptr, nullptr, preA, nullptr);
  lstm_k<2, PreT><<<BB, 256, 0, stream>>>(nullptr, preA, nullptr, whh_a2, bih_a2, bhh_a2,
                                          wih_b0, bih_b0, bhh_b0, nullptr, pb0);
  b_rec_k<<<1, 256, 0, stream>>>(pb0, whh_b0, wih_b1, whh_b1, bih_b1, bhh_b1,
                                 wih_b2, whh_b2, bih_b2, bhh_b2, out);
}

extern "C" void kernel_launch(void* const* d_in, const int* in_sizes, int n_in,
                              void* d_out, int out_size, void* d_ws, size_t ws_size,
                              hipStream_t stream) {
  const size_t need_f32 = (size_t)BB * TT * 256 * 4 + (size_t)TT * BB * 4 * 4;
  if (ws_size >= need_f32) {
    launch_all<float>(d_in, d_out, d_ws, stream);
  } else {
    launch_all<_Float16>(d_in, d_out, d_ws, stream);
  }
}